// Round 1
// baseline (1395.356 us; speedup 1.0000x reference)
//
#include <hip/hip_runtime.h>
#include <hip/hip_bf16.h>

#define BB 8
#define CC 128
#define HH 128
#define WW 128
#define HW (HH*WW)
#define MD 3
#define ND 49
#define WARP_WEIGHT 2.5f
#define NEG 0.1f

// ---------------- flow upsample (bilinear x2, align_corners=False) ----------------
__global__ void k_flow_up(const float* __restrict__ flow, float* __restrict__ flow_up) {
    // flow: [B,2,64,64] -> flow_up: [B,2,128,128]
    const int x = threadIdx.x;      // 0..127
    const int y = blockIdx.x;       // 0..127
    const int c = blockIdx.y;       // 0..1
    const int b = blockIdx.z;       // 0..7
    const int Hs = 64, Ws = 64;
    float sy = (y + 0.5f) * 0.5f - 0.5f;
    float sx = (x + 0.5f) * 0.5f - 0.5f;
    float y0f = floorf(sy), x0f = floorf(sx);
    int y0 = (int)y0f, x0 = (int)x0f;
    float wy = sy - y0f, wx = sx - x0f;
    int y0c = min(max(y0, 0), Hs - 1), y1c = min(max(y0 + 1, 0), Hs - 1);
    int x0c = min(max(x0, 0), Ws - 1), x1c = min(max(x0 + 1, 0), Ws - 1);
    const float* src = flow + ((size_t)(b * 2 + c)) * Hs * Ws;
    float v00 = src[y0c * Ws + x0c], v01 = src[y0c * Ws + x1c];
    float v10 = src[y1c * Ws + x0c], v11 = src[y1c * Ws + x1c];
    float v = v00 * (1.f - wx) * (1.f - wy) + v01 * wx * (1.f - wy)
            + v10 * (1.f - wx) * wy + v11 * wx * wy;
    flow_up[((size_t)(b * 2 + c) * HH + y) * WW + x] = v;
}

// ---------------- backward warp of features2 ----------------
__global__ void k_warp(const float* __restrict__ f2, const float* __restrict__ flow_up,
                       float* __restrict__ f2w) {
    const int x = threadIdx.x;      // 0..127
    const int y = blockIdx.x;       // 0..127
    const int c = blockIdx.y;       // 0..127
    const int b = blockIdx.z;       // 0..7
    const float fx = flow_up[((size_t)(b * 2 + 0) * HH + y) * WW + x] * WARP_WEIGHT;
    const float fy = flow_up[((size_t)(b * 2 + 1) * HH + y) * WW + x] * WARP_WEIGHT;
    const float sx = (float)x + fx;
    const float sy = (float)y + fy;
    float x0f = floorf(sx), y0f = floorf(sy);
    int x0 = (int)x0f, y0 = (int)y0f;
    float wx = sx - x0f, wy = sy - y0f;
    const float* img = f2 + ((size_t)(b * CC + c)) * HW;
    auto g = [&](int yi, int xi) -> float {
        bool valid = (yi >= 0) && (yi < HH) && (xi >= 0) && (xi < WW);
        int yc = min(max(yi, 0), HH - 1);
        int xc = min(max(xi, 0), WW - 1);
        float v = img[yc * WW + xc];
        return valid ? v : 0.f;
    };
    float v = g(y0, x0) * (1.f - wx) * (1.f - wy)
            + g(y0, x0 + 1) * wx * (1.f - wy)
            + g(y0 + 1, x0) * (1.f - wx) * wy
            + g(y0 + 1, x0 + 1) * wx * wy;
    f2w[((size_t)(b * CC + c)) * HW + y * WW + x] = v;
}

// ---------------- 7x7 cost volume, mean over C ----------------
__global__ void k_corr(const float* __restrict__ f1, const float* __restrict__ f2w,
                       float* __restrict__ corr) {
    const int x = threadIdx.x;      // 0..127
    const int y = blockIdx.x;       // 0..127
    const int b = blockIdx.y;       // 0..7
    float acc[ND];
#pragma unroll
    for (int i = 0; i < ND; i++) acc[i] = 0.f;
    const float* p1 = f1 + (size_t)b * CC * HW + y * WW + x;
    const float* p2base = f2w + (size_t)b * CC * HW;
    for (int c = 0; c < CC; c++) {
        float v1 = p1[(size_t)c * HW];
        const float* p2 = p2base + (size_t)c * HW;
#pragma unroll
        for (int dy = 0; dy < 7; dy++) {
            int yy = y + dy - MD;
            bool yv = (yy >= 0) && (yy < HH);
#pragma unroll
            for (int dx = 0; dx < 7; dx++) {
                int xx = x + dx - MD;
                float v2 = (yv && xx >= 0 && xx < WW) ? p2[yy * WW + xx] : 0.f;
                acc[dy * 7 + dx] += v1 * v2;
            }
        }
    }
    const float scale = 1.f / (float)CC;
#pragma unroll
    for (int d = 0; d < ND; d++)
        corr[(((size_t)b * ND + d) * HH + y) * WW + x] = acc[d] * scale;
}

// ---------------- direct conv (3x3), optional leaky relu ----------------
template<int IC, int K, int PAD, bool RELU>
__global__ void k_conv(const float* __restrict__ in, const float* __restrict__ w,
                       const float* __restrict__ bias, float* __restrict__ out, int OC) {
    const int x = threadIdx.x;      // 0..127
    const int y = blockIdx.x;       // 0..127
    const int oc = blockIdx.y;
    const int b = blockIdx.z;
    float acc = bias[oc];
    const float* wp = w + (size_t)oc * IC * K * K;
    const float* ip = in + (size_t)b * IC * HW;
    for (int ic = 0; ic < IC; ic++) {
#pragma unroll
        for (int kh = 0; kh < K; kh++) {
            int yy = y + kh - PAD;
            if (yy < 0 || yy >= HH) continue;
#pragma unroll
            for (int kw = 0; kw < K; kw++) {
                int xx = x + kw - PAD;
                float v = (xx >= 0 && xx < WW) ? ip[(size_t)ic * HW + yy * WW + xx] : 0.f;
                acc += v * wp[(ic * K + kh) * K + kw];
            }
        }
    }
    if (RELU) acc = (acc >= 0.f) ? acc : NEG * acc;
    out[(((size_t)b * OC + oc) * HH + y) * WW + x] = acc;
}

// ---------------- final 5x5 conv + flow_up add ----------------
__global__ void k_conv3_add(const float* __restrict__ in, const float* __restrict__ w,
                            const float* __restrict__ bias, const float* __restrict__ flow_up,
                            float* __restrict__ out) {
    const int x = threadIdx.x;
    const int y = blockIdx.x;
    const int oc = blockIdx.y;      // 0..1
    const int b = blockIdx.z;
    float acc = bias[oc];
    const float* wp = w + (size_t)oc * 32 * 25;
    const float* ip = in + (size_t)b * 32 * HW;
    for (int ic = 0; ic < 32; ic++) {
#pragma unroll
        for (int kh = 0; kh < 5; kh++) {
            int yy = y + kh - 2;
            if (yy < 0 || yy >= HH) continue;
#pragma unroll
            for (int kw = 0; kw < 5; kw++) {
                int xx = x + kw - 2;
                float v = (xx >= 0 && xx < WW) ? ip[(size_t)ic * HW + yy * WW + xx] : 0.f;
                acc += v * wp[(ic * 5 + kh) * 5 + kw];
            }
        }
    }
    size_t o = (((size_t)b * 2 + oc) * HH + y) * WW + x;
    out[o] = acc + flow_up[o];
}

extern "C" void kernel_launch(void* const* d_in, const int* in_sizes, int n_in,
                              void* d_out, int out_size, void* d_ws, size_t ws_size,
                              hipStream_t stream) {
    const float* f1   = (const float*)d_in[0];
    const float* f2   = (const float*)d_in[1];
    const float* flow = (const float*)d_in[2];
    const float* w1   = (const float*)d_in[3];
    const float* b1   = (const float*)d_in[4];
    const float* w2   = (const float*)d_in[5];
    const float* b2   = (const float*)d_in[6];
    const float* w3   = (const float*)d_in[7];
    const float* b3   = (const float*)d_in[8];
    float* out = (float*)d_out;

    char* ws = (char*)d_ws;
    const size_t SZ_FLOWUP = (size_t)BB * 2 * HW * 4;        // 1 MB
    const size_t SZ_F2W    = (size_t)BB * CC * HW * 4;       // 64 MB
    float* flow_up = (float*)ws;
    float* f2w     = (float*)(ws + SZ_FLOWUP);
    float* corr    = (float*)(ws + SZ_FLOWUP + SZ_F2W);      // 25.7 MB
    // h1/h2 reuse the f2w region (f2w dead after corr is computed)
    float* h1      = f2w;                                     // 33.5 MB
    float* h2      = (float*)((char*)f2w + (size_t)BB * 64 * HW * 4); // 16.8 MB

    dim3 blk(WW);
    k_flow_up<<<dim3(HH, 2, BB),   blk, 0, stream>>>(flow, flow_up);
    k_warp   <<<dim3(HH, CC, BB),  blk, 0, stream>>>(f2, flow_up, f2w);
    k_corr   <<<dim3(HH, BB),      blk, 0, stream>>>(f1, f2w, corr);
    k_conv<49, 3, 1, true><<<dim3(HH, 64, BB), blk, 0, stream>>>(corr, w1, b1, h1, 64);
    k_conv<64, 3, 1, true><<<dim3(HH, 32, BB), blk, 0, stream>>>(h1, w2, b2, h2, 32);
    k_conv3_add<<<dim3(HH, 2, BB), blk, 0, stream>>>(h2, w3, b3, flow_up, out);
}

// Round 2
// 345.911 us; speedup vs baseline: 4.0339x; 4.0339x over previous
//
#include <hip/hip_runtime.h>
#include <hip/hip_bf16.h>

#define BB 8
#define CC 128
#define HH 128
#define WW 128
#define HW (HH*WW)
#define MD 3
#define ND 49
#define WARP_WEIGHT 2.5f
#define NEG 0.1f

typedef __attribute__((ext_vector_type(8))) short bf16x8;
typedef __attribute__((ext_vector_type(4))) float f32x4;

__device__ inline ushort f2bf(float f) {
    __hip_bfloat16 h = __float2bfloat16(f);
    return *reinterpret_cast<ushort*>(&h);
}

// ---------------- flow upsample (bilinear x2, align_corners=False) ----------------
__global__ void k_flow_up(const float* __restrict__ flow, float* __restrict__ flow_up) {
    const int x = threadIdx.x;      // 0..127
    const int y = blockIdx.x;       // 0..127
    const int c = blockIdx.y;       // 0..1
    const int b = blockIdx.z;       // 0..7
    const int Hs = 64, Ws = 64;
    float sy = (y + 0.5f) * 0.5f - 0.5f;
    float sx = (x + 0.5f) * 0.5f - 0.5f;
    float y0f = floorf(sy), x0f = floorf(sx);
    int y0 = (int)y0f, x0 = (int)x0f;
    float wy = sy - y0f, wx = sx - x0f;
    int y0c = min(max(y0, 0), Hs - 1), y1c = min(max(y0 + 1, 0), Hs - 1);
    int x0c = min(max(x0, 0), Ws - 1), x1c = min(max(x0 + 1, 0), Ws - 1);
    const float* src = flow + ((size_t)(b * 2 + c)) * Hs * Ws;
    float v00 = src[y0c * Ws + x0c], v01 = src[y0c * Ws + x1c];
    float v10 = src[y1c * Ws + x0c], v11 = src[y1c * Ws + x1c];
    float v = v00 * (1.f - wx) * (1.f - wy) + v01 * wx * (1.f - wy)
            + v10 * (1.f - wx) * wy + v11 * wx * wy;
    flow_up[((size_t)(b * 2 + c) * HH + y) * WW + x] = v;
}

// ---------------- backward warp of features2 (f32 planar out) ----------------
__global__ void k_warp(const float* __restrict__ f2, const float* __restrict__ flow_up,
                       float* __restrict__ f2w) {
    const int x = threadIdx.x;
    const int y = blockIdx.x;
    const int c = blockIdx.y;
    const int b = blockIdx.z;
    const float fx = flow_up[((size_t)(b * 2 + 0) * HH + y) * WW + x] * WARP_WEIGHT;
    const float fy = flow_up[((size_t)(b * 2 + 1) * HH + y) * WW + x] * WARP_WEIGHT;
    const float sx = (float)x + fx;
    const float sy = (float)y + fy;
    float x0f = floorf(sx), y0f = floorf(sy);
    int x0 = (int)x0f, y0 = (int)y0f;
    float wx = sx - x0f, wy = sy - y0f;
    const float* img = f2 + ((size_t)(b * CC + c)) * HW;
    auto g = [&](int yi, int xi) -> float {
        bool valid = (yi >= 0) && (yi < HH) && (xi >= 0) && (xi < WW);
        int yc = min(max(yi, 0), HH - 1);
        int xc = min(max(xi, 0), WW - 1);
        float v = img[yc * WW + xc];
        return valid ? v : 0.f;
    };
    float v = g(y0, x0) * (1.f - wx) * (1.f - wy)
            + g(y0, x0 + 1) * wx * (1.f - wy)
            + g(y0 + 1, x0) * (1.f - wx) * wy
            + g(y0 + 1, x0 + 1) * wx * wy;
    f2w[((size_t)(b * CC + c)) * HW + y * WW + x] = v;
}

// ---------------- 7x7 cost volume, mean over C; writes bf16 channel-last padded ----------------
__global__ __launch_bounds__(128) void k_corr(const float* __restrict__ f1,
                                              const float* __restrict__ f2w,
                                              ushort* __restrict__ Ct) {
    const int x = threadIdx.x;
    const int y = blockIdx.x;
    const int b = blockIdx.y;
    float acc[ND];
#pragma unroll
    for (int i = 0; i < ND; i++) acc[i] = 0.f;
    const float* p1 = f1 + (size_t)b * CC * HW + y * WW + x;
    const float* p2base = f2w + (size_t)b * CC * HW;
    for (int c = 0; c < CC; c++) {
        float v1 = p1[(size_t)c * HW];
        const float* p2 = p2base + (size_t)c * HW;
#pragma unroll
        for (int dy = 0; dy < 7; dy++) {
            int yy = y + dy - MD;
            bool yv = (yy >= 0) && (yy < HH);
#pragma unroll
            for (int dx = 0; dx < 7; dx++) {
                int xx = x + dx - MD;
                float v2 = (yv && xx >= 0 && xx < WW) ? p2[yy * WW + xx] : 0.f;
                acc[dy * 7 + dx] += v1 * v2;
            }
        }
    }
    const float scale = 1.f / (float)CC;
    ushort tmp[64];
#pragma unroll
    for (int d = 0; d < ND; d++) tmp[d] = f2bf(acc[d] * scale);
#pragma unroll
    for (int d = ND; d < 64; d++) tmp[d] = 0;
    uint4* dst = reinterpret_cast<uint4*>(Ct + (((size_t)b * HH + y) * WW + x) * 64);
    const uint4* src = reinterpret_cast<const uint4*>(tmp);
#pragma unroll
    for (int i = 0; i < 8; i++) dst[i] = src[i];
}

// ---------------- weight transpose + bf16: w[OC][IC][K][K] -> Wt[K*K][OCP][ICP] ----------------
template<int IC, int ICP, int OC, int OCP, int KK>
__global__ void k_prep_w(const float* __restrict__ w, ushort* __restrict__ Wt) {
    int e = blockIdx.x * 256 + threadIdx.x;
    const int total = KK * KK * OCP * ICP;
    if (e >= total) return;
    int ic = e % ICP;
    int oc = (e / ICP) % OCP;
    int tap = e / (ICP * OCP);
    int kh = tap / KK, kw = tap % KK;
    float v = 0.f;
    if (oc < OC && ic < IC) v = w[((oc * IC + ic) * KK + kh) * KK + kw];
    Wt[e] = f2bf(v);
}

// ---------------- implicit-GEMM MFMA conv ----------------
// In: [B][H][W][ICP] bf16, Wt: [K*K][OCP][ICP] bf16, Out: [B][H][W][OCOUT] bf16
// LAST: write f32 out[b][oc][y][x] = acc + bias + flow_up (oc<2)
template<int ICP, int OCP, int OCOUT, int KK, int PAD, bool RELU, bool LAST>
__global__ __launch_bounds__(128) void k_conv_mfma(
    const ushort* __restrict__ In, const ushort* __restrict__ Wt,
    const float* __restrict__ bias, ushort* __restrict__ Out,
    const float* __restrict__ flow_up, float* __restrict__ fout)
{
    constexpr int MT = OCP / 16;    // m-tiles
    constexpr int NCH = ICP / 32;   // K chunks per tap
    const int y = blockIdx.x;
    const int b = blockIdx.y;
    const int l = threadIdx.x & 63;
    const int n0 = (threadIdx.x >> 6) * 64;   // wave's x-base (2 waves/block)
    const int lx = l & 15;
    const int lk = l >> 4;

    f32x4 acc[MT][4];
#pragma unroll
    for (int m = 0; m < MT; m++)
#pragma unroll
        for (int nt = 0; nt < 4; nt++) acc[m][nt] = (f32x4)(0.f);

    for (int kh = 0; kh < KK; kh++) {
        int yy = y + kh - PAD;
        if (yy < 0 || yy >= HH) continue;
        const ushort* inrow = In + ((size_t)(b * HH + yy)) * WW * ICP;
#pragma unroll
        for (int kw = 0; kw < KK; kw++) {
            const ushort* wtap = Wt + (size_t)(kh * KK + kw) * OCP * ICP;
#pragma unroll
            for (int ch = 0; ch < NCH; ch++) {
                const int k0 = ch * 32 + lk * 8;
                bf16x8 a[MT];
#pragma unroll
                for (int m = 0; m < MT; m++)
                    a[m] = *reinterpret_cast<const bf16x8*>(wtap + (m * 16 + lx) * ICP + k0);
#pragma unroll
                for (int nt = 0; nt < 4; nt++) {
                    int xx = n0 + nt * 16 + lx + kw - PAD;
                    bf16x8 bf = {};
                    if ((unsigned)xx < (unsigned)WW)
                        bf = *reinterpret_cast<const bf16x8*>(inrow + (size_t)xx * ICP + k0);
#pragma unroll
                    for (int m = 0; m < MT; m++)
                        acc[m][nt] = __builtin_amdgcn_mfma_f32_16x16x32_bf16(a[m], bf, acc[m][nt], 0, 0, 0);
                }
            }
        }
    }

    if (!LAST) {
#pragma unroll
        for (int m = 0; m < MT; m++) {
            const int oc0 = m * 16 + lk * 4;
            float4 bs = *reinterpret_cast<const float4*>(bias + oc0);
#pragma unroll
            for (int nt = 0; nt < 4; nt++) {
                int x = n0 + nt * 16 + lx;
                float v0 = acc[m][nt][0] + bs.x;
                float v1 = acc[m][nt][1] + bs.y;
                float v2 = acc[m][nt][2] + bs.z;
                float v3 = acc[m][nt][3] + bs.w;
                if (RELU) {
                    v0 = (v0 >= 0.f) ? v0 : NEG * v0;
                    v1 = (v1 >= 0.f) ? v1 : NEG * v1;
                    v2 = (v2 >= 0.f) ? v2 : NEG * v2;
                    v3 = (v3 >= 0.f) ? v3 : NEG * v3;
                }
                ushort4 o;
                o.x = f2bf(v0); o.y = f2bf(v1); o.z = f2bf(v2); o.w = f2bf(v3);
                *reinterpret_cast<ushort4*>(Out + (((size_t)(b * HH + y)) * WW + x) * OCOUT + oc0) = o;
            }
        }
    } else {
        if (lk == 0) {   // oc = lk*4 + r, need oc<2
#pragma unroll
            for (int nt = 0; nt < 4; nt++) {
                int x = n0 + nt * 16 + lx;
#pragma unroll
                for (int r = 0; r < 2; r++) {
                    size_t o = (((size_t)(b * 2 + r)) * HH + y) * WW + x;
                    fout[o] = acc[0][nt][r] + bias[r] + flow_up[o];
                }
            }
        }
    }
}

extern "C" void kernel_launch(void* const* d_in, const int* in_sizes, int n_in,
                              void* d_out, int out_size, void* d_ws, size_t ws_size,
                              hipStream_t stream) {
    const float* f1   = (const float*)d_in[0];
    const float* f2   = (const float*)d_in[1];
    const float* flow = (const float*)d_in[2];
    const float* w1   = (const float*)d_in[3];
    const float* b1   = (const float*)d_in[4];
    const float* w2   = (const float*)d_in[5];
    const float* b2   = (const float*)d_in[6];
    const float* w3   = (const float*)d_in[7];
    const float* b3   = (const float*)d_in[8];
    float* out = (float*)d_out;

    char* ws = (char*)d_ws;
    // layout (bytes):
    const size_t SZ_FLOWUP = (size_t)BB * 2 * HW * 4;          // 1.0 MB
    const size_t SZ_CT     = (size_t)BB * HW * 64 * 2;         // 16.8 MB
    const size_t SZ_WT1    = (size_t)9 * 64 * 64 * 2;          // 73.7 KB
    const size_t SZ_WT2    = (size_t)9 * 32 * 64 * 2;          // 36.9 KB
    const size_t SZ_WT3    = (size_t)25 * 16 * 32 * 2;         // 25.6 KB
    const size_t SZ_F2W    = (size_t)BB * CC * HW * 4;         // 64 MB

    float*  flow_up = (float*)ws;                         ws += SZ_FLOWUP;
    ushort* Ct      = (ushort*)ws;                        ws += SZ_CT;
    ushort* Wt1     = (ushort*)ws;                        ws += SZ_WT1;
    ushort* Wt2     = (ushort*)ws;                        ws += SZ_WT2;
    ushort* Wt3     = (ushort*)ws;                        ws += SZ_WT3;
    float*  f2w     = (float*)ws;                         // 64 MB region
    // h1/h2 alias f2w (dead after k_corr)
    ushort* h1      = (ushort*)f2w;                                   // 16.8 MB
    ushort* h2      = (ushort*)((char*)f2w + (size_t)BB * HW * 64 * 2); // 8.4 MB

    dim3 blk(WW);
    k_prep_w<49, 64, 64, 64, 3><<<dim3((9 * 64 * 64 + 255) / 256), dim3(256), 0, stream>>>(w1, Wt1);
    k_prep_w<64, 64, 32, 32, 3><<<dim3((9 * 32 * 64 + 255) / 256), dim3(256), 0, stream>>>(w2, Wt2);
    k_prep_w<32, 32, 2, 16, 5><<<dim3((25 * 16 * 32 + 255) / 256), dim3(256), 0, stream>>>(w3, Wt3);

    k_flow_up<<<dim3(HH, 2, BB),  blk, 0, stream>>>(flow, flow_up);
    k_warp   <<<dim3(HH, CC, BB), blk, 0, stream>>>(f2, flow_up, f2w);
    k_corr   <<<dim3(HH, BB),     blk, 0, stream>>>(f1, f2w, Ct);

    k_conv_mfma<64, 64, 64, 3, 1, true,  false><<<dim3(HH, BB), dim3(128), 0, stream>>>(
        Ct, Wt1, b1, h1, nullptr, nullptr);
    k_conv_mfma<64, 32, 32, 3, 1, true,  false><<<dim3(HH, BB), dim3(128), 0, stream>>>(
        h1, Wt2, b2, h2, nullptr, nullptr);
    k_conv_mfma<32, 16, 2,  5, 2, false, true ><<<dim3(HH, BB), dim3(128), 0, stream>>>(
        h2, Wt3, b3, nullptr, flow_up, out);
}